// Round 12
// baseline (18724.954 us; speedup 1.0000x reference)
//
#include <hip/hip_runtime.h>
#include <math.h>

// Problem constants (from reference)
#define Bsz   32
#define Lmem  512
#define Tsteps 400
#define EMBD  512
#define PRE   256
#define ENCD  512
#define ARNN  1024
#define DRNN  1024
#define NSYM  256
// MEAN_COEFF = 1.0f, SCALE_COEFF = 10.0f

typedef _Float16 f16x8 __attribute__((ext_vector_type(8)));
typedef float    f32x4 __attribute__((ext_vector_type(4)));
typedef _Float16 half_t;

// Unified K-layouts (weights repacked to match):
//   A: [xpre(0:256) | ah(256:1280) | ctx(1280:1792)]   KA=1792
//   D: [ah(0:1024) | dh(1024:2048) | ctx(2048:2560)]   KD=2560
#define KA  1792
#define KAQ 448
#define NMA 14
#define CTXA0 1280
#define KD  2560
#define KDQ 640
#define NMD 20
#define CTXD0 2048
#define LDA_A 1800                 // KA + 8 pad (LDS)
#define LDA_D 2568                 // KD + 8 pad (LDS)

// ---- agent-scope (cross-XCD) access: sc1 bypasses the non-coherent per-XCD
// L2 to the L3 coherence point. Mutable cross-block data: sc1 loads+stores.
// Read-only data: plain loads (L2-hot). No cache-invalidate fences anywhere.
__device__ __forceinline__ void st_agent_f32(float* p, float v) {
    __hip_atomic_store(p, v, __ATOMIC_RELAXED, __HIP_MEMORY_SCOPE_AGENT);
}
__device__ __forceinline__ void st_agent_u32(unsigned* p, unsigned v) {
    __hip_atomic_store(p, v, __ATOMIC_RELAXED, __HIP_MEMORY_SCOPE_AGENT);
}
__device__ __forceinline__ void st_agent_u64(unsigned long long* p, unsigned long long v) {
    __hip_atomic_store(p, v, __ATOMIC_RELAXED, __HIP_MEMORY_SCOPE_AGENT);
}
__device__ __forceinline__ float ld_agent_f32(const float* p) {
    return __hip_atomic_load(p, __ATOMIC_RELAXED, __HIP_MEMORY_SCOPE_AGENT);
}
__device__ __forceinline__ unsigned ld_agent_u32(const unsigned* p) {
    return __hip_atomic_load(p, __ATOMIC_RELAXED, __HIP_MEMORY_SCOPE_AGENT);
}
__device__ __forceinline__ unsigned long long ld_agent_u64(const unsigned long long* p) {
    return __hip_atomic_load(p, __ATOMIC_RELAXED, __HIP_MEMORY_SCOPE_AGENT);
}
__device__ __forceinline__ f16x8 ld_agent_f16x8(const half_t* p) {
    union { unsigned long long u[2]; f16x8 v; } c;
    c.u[0] = __hip_atomic_load((const unsigned long long*)p,
                               __ATOMIC_RELAXED, __HIP_MEMORY_SCOPE_AGENT);
    c.u[1] = __hip_atomic_load(((const unsigned long long*)p) + 1,
                               __ATOMIC_RELAXED, __HIP_MEMORY_SCOPE_AGENT);
    return c.v;
}
// Pin a prefetched fragment (guide rule #17).
__device__ __forceinline__ void keep16(f16x8& v) { asm volatile("" : "+v"(v)); }
// Compact tanh: 1 - 2/(e^{2x}+1); exact at +-inf saturation.
__device__ __forceinline__ float tanh_f(float x) {
    return 1.f - 2.f / (expf(2.f * x) + 1.f);
}

// ---------------------------------------------------------------------------
// One-time weight packing: permuted to the unified K-layout.
// dst[k] = Wih[k]          for k < L0
//          Whh[k-L0]       for L0 <= k < L0+KHH
//          Wih[k-KHH]      for k >= L0+KHH       (the tail of Wih = ctx part)
// ---------------------------------------------------------------------------
template<int KIH, int KHH, int L0>
__global__ __launch_bounds__(256) void conv_lstm_w(
    const float* __restrict__ Wih, const float* __restrict__ Whh,
    const float* __restrict__ bih, const float* __restrict__ bhh,
    half_t* __restrict__ Wcat, float* __restrict__ bsum)
{
    constexpr int K = KIH + KHH;
    const int j = blockIdx.x;
    const float* srcA = Wih + (size_t)j * KIH;
    const float* srcB = Whh + (size_t)j * KHH;
    half_t* dst = Wcat + (size_t)j * K;
    for (int k = threadIdx.x; k < L0; k += 256)        dst[k] = (half_t)srcA[k];
    for (int k = threadIdx.x; k < KHH; k += 256)       dst[L0 + k] = (half_t)srcB[k];
    for (int k = L0 + threadIdx.x; k < KIH; k += 256)  dst[KHH + k] = (half_t)srcA[k];
    if (threadIdx.x == 0) bsum[j] = bih[j] + bhh[j];
}

__global__ __launch_bounds__(256) void conv_mat(
    const float* __restrict__ src, half_t* __restrict__ dst, int n)
{
    for (int i = blockIdx.x * 256 + threadIdx.x; i < n; i += gridDim.x * 256)
        dst[i] = (half_t)src[i];
}

// copy xpre_0 into actA[0] slot [0,256) per batch (one-time)
__global__ __launch_bounds__(128) void xpre0_copy(
    const half_t* __restrict__ xpre, half_t* __restrict__ actA0)
{
    const int b = blockIdx.x;
    if (threadIdx.x < 64) {
        const unsigned long long* s = (const unsigned long long*)(xpre + b * PRE);
        unsigned long long* d = (unsigned long long*)(actA0 + (size_t)b * KA);
        d[threadIdx.x] = s[threadIdx.x];
    }
}

// ---------------------------------------------------------------------------
// Prenet (one-time, parallel over T*B rows): f16 output (T,B,PRE)
// ---------------------------------------------------------------------------
__global__ __launch_bounds__(256) void prenet_kernel(
    const float* __restrict__ din,
    const float* __restrict__ pW1, const float* __restrict__ pb1,
    const float* __restrict__ pW2, const float* __restrict__ pb2,
    half_t* __restrict__ xpre)
{
    __shared__ float xs[8][EMBD];
    __shared__ float h1s[8][PRE];
    const int tid = threadIdx.x;
    const int row0 = blockIdx.x * 8;

    for (int idx = tid; idx < 8 * EMBD; idx += 256) {
        int r = idx >> 9;
        int e = idx & 511;
        int rid = row0 + r;
        int t = rid >> 5;
        int b = rid & 31;
        float v = 0.f;
        if (t > 0) v = din[(size_t)b * EMBD * Tsteps + (size_t)e * Tsteps + (t - 1)];
        xs[r][e] = v;
    }
    __syncthreads();

    {
        float acc[8] = {0.f,0.f,0.f,0.f,0.f,0.f,0.f,0.f};
        const float* wr = pW1 + (size_t)tid * EMBD;
        for (int e = 0; e < EMBD; e += 4) {
            float4 wv = *(const float4*)(wr + e);
            #pragma unroll
            for (int r = 0; r < 8; ++r) {
                float4 xv = *(const float4*)&xs[r][e];
                acc[r] += wv.x * xv.x + wv.y * xv.y + wv.z * xv.z + wv.w * xv.w;
            }
        }
        float bias = pb1[tid];
        #pragma unroll
        for (int r = 0; r < 8; ++r) h1s[r][tid] = fmaxf(acc[r] + bias, 0.f);
    }
    __syncthreads();

    {
        float acc[8] = {0.f,0.f,0.f,0.f,0.f,0.f,0.f,0.f};
        const float* wr = pW2 + (size_t)tid * PRE;
        for (int e = 0; e < PRE; e += 4) {
            float4 wv = *(const float4*)(wr + e);
            #pragma unroll
            for (int r = 0; r < 8; ++r) {
                float4 xv = *(const float4*)&h1s[r][e];
                acc[r] += wv.x * xv.x + wv.y * xv.y + wv.z * xv.z + wv.w * xv.w;
            }
        }
        float bias = pb2[tid];
        #pragma unroll
        for (int r = 0; r < 8; ++r) {
            int rid = row0 + r;
            int t = rid >> 5;
            int b = rid & 31;
            xpre[(size_t)t * Bsz * PRE + (size_t)b * PRE + tid] =
                (half_t)fmaxf(acc[r] + bias, 0.f);
        }
    }
}

// ---------------------------------------------------------------------------
// 2-level bounded-fan-in barrier (R10, known-good). All sc1, RMW-free.
// ---------------------------------------------------------------------------
__device__ __forceinline__ void g_arrive(unsigned* flags, unsigned ph)
{
    asm volatile("s_waitcnt vmcnt(0)" ::: "memory");
    __syncthreads();
    if (threadIdx.x == 0)
        st_agent_u32(flags + blockIdx.x * 16, ph);
}
__device__ __forceinline__ void g_wait(unsigned* flags, unsigned ph, int grp, int grank)
{
    if (grank == 0) {
        if (threadIdx.x < 32) {
            const unsigned* f = flags + (grp * 32 + threadIdx.x) * 16;
            while (ld_agent_u32(f) < ph) __builtin_amdgcn_s_sleep(1);
        }
        if (threadIdx.x == 0)
            st_agent_u32(flags + (256 + grp) * 16, ph);
        if (threadIdx.x < 8) {
            const unsigned* f2 = flags + (256 + threadIdx.x) * 16;
            while (ld_agent_u32(f2) < ph) __builtin_amdgcn_s_sleep(1);
        }
        if (threadIdx.x == 0)
            st_agent_u32(flags + (264 + grp) * 16, ph);
    } else {
        if (threadIdx.x == 0) {
            const unsigned* g = flags + (264 + grp) * 16;
            while (ld_agent_u32(g) < ph) __builtin_amdgcn_s_sleep(1);
        }
    }
    __syncthreads();
}

// ---------------------------------------------------------------------------
// Persistent decoder. 256 blocks x 512 threads. Weights in LDS all 400 steps.
// Unified activation buffers actA/actD (double-buffered): every B-fragment
// load is a uniform strided sc1 load — no segment selects in the hot loop.
// Pipeline (2 barriers/step):
//   ph1: aLSTM_t || dLSTM_{t-1} || outproj_{t-2} (+partials, +xpre copy)
//   ph2: att_t
// ctx is the LAST K-slot, so the bar2 window prefetches all non-ctx
// fragments (wave-uniform boundary preA/preD); ctx tail loads post-wait.
// ---------------------------------------------------------------------------
__global__ __launch_bounds__(512, 2) void decoder_persistent(
    const half_t* __restrict__ Wcat_a, const float* __restrict__ bsum_a,
    const half_t* __restrict__ Wcat_d, const float* __restrict__ bsum_d,
    const half_t* __restrict__ Wo, const float* __restrict__ ob,
    const half_t* __restrict__ xpre,
    const float* __restrict__ attWp, const float* __restrict__ attbp,
    const int* __restrict__ mlen, const half_t* __restrict__ mem16,
    half_t* __restrict__ actA, half_t* __restrict__ actD,   // [2][32][K]
    float* __restrict__ mean0, float* __restrict__ mean1,
    float* __restrict__ partials,   // [32][256][2] f32
    float* __restrict__ logits, float* __restrict__ aligns,
    float* __restrict__ ps,
    unsigned* flags)
{
    const int blk   = blockIdx.x;
    const int tid   = threadIdx.x;
    const int wave  = tid >> 6;
    const int lane  = tid & 63;
    const int btile = wave & 1;
    const int kq    = wave >> 1;
    const int m15   = lane & 15;
    const int kh    = lane >> 4;
    const int u0    = blk << 2;
    const int bb    = (btile << 4) + m15;
    const int grp   = blk >> 5;
    const int grank = blk & 31;

    const int preA = min(NMA, max(0, (CTXA0 - kq * KAQ) >> 5));
    const int preD = min(NMD, max(0, (CTXD0 - kq * KDQ) >> 5));

    __shared__ __align__(16) half_t wAl[16 * LDA_A];   // 57.6 KB
    __shared__ __align__(16) half_t wDl[16 * LDA_D];   // 82.2 KB
    __shared__ float gredA[4][2][16][16];              // 8 KB
    __shared__ float gredD[4][2][16][16];              // 8 KB
    __shared__ float wsh[Lmem];                        // 2 KB
    __shared__ float lred[16][33];                     // 2.1 KB
    __shared__ float part[4][32][2];                   // 1 KB
    __shared__ half_t hstA[4][32];                     // 256 B
    __shared__ half_t hstD[4][32];                     // 256 B
    __shared__ float wred8[8][2];
    __shared__ float bc2[2];

    // ---- stage weight rows into LDS (one-time) ----
    for (int g = tid; g < 16 * (KA / 8); g += 512) {
        int r = g / (KA / 8);
        int c = (g - r * (KA / 8)) * 8;
        int jr = (r >> 2) * 1024 + u0 + (r & 3);
        *(f16x8*)(wAl + r * LDA_A + c) = *(const f16x8*)(Wcat_a + (size_t)jr * KA + c);
    }
    for (int g = tid; g < 16 * (KD / 8); g += 512) {
        int r = g / (KD / 8);
        int c = (g - r * (KD / 8)) * 8;
        int jr = (r >> 2) * 1024 + u0 + (r & 3);
        *(f16x8*)(wDl + r * LDA_D + c) = *(const f16x8*)(Wcat_d + (size_t)jr * KD + c);
    }
    // epilogue biases + attWp slice
    float bsA[4] = {0.f,0.f,0.f,0.f}, bsD[4] = {0.f,0.f,0.f,0.f};
    float wp0 = 0.f, wp1 = 0.f;
    float cA = 0.f, cD = 0.f;
    if (tid < 128) {
        const int ul = tid >> 5;
        #pragma unroll
        for (int gi = 0; gi < 4; ++gi) bsA[gi] = bsum_a[gi * 1024 + u0 + ul];
        wp0 = attWp[u0 + ul];
        wp1 = attWp[ARNN + u0 + ul];
    } else if (tid < 256) {
        const int ul = (tid - 128) >> 5;
        #pragma unroll
        for (int gi = 0; gi < 4; ++gi) bsD[gi] = bsum_d[gi * 1024 + u0 + ul];
    }
    const half_t* lA = wAl + m15 * LDA_A + kq * KAQ + (kh << 3);
    const half_t* lD = wDl + m15 * LDA_D + kq * KDQ + (kh << 3);
    __syncthreads();

    // ---- initial bvA from actA[0] (xpre0 copied; ah/ctx zero) — plain ----
    f16x8 bvA[NMA], bvD[NMD];
    {
        const half_t* b0 = actA + (size_t)bb * KA + kq * KAQ + (kh << 3);
        #pragma unroll
        for (int i = 0; i < NMA; ++i) bvA[i] = *(const f16x8*)(b0 + i * 32);
    }

    unsigned ph = 0;

    for (int t = 0; t <= Tsteps + 1; ++t) {
        const int par = t & 1;
        half_t* actA_R = actA + (size_t)(par) * Bsz * KA;
        half_t* actA_W = actA + (size_t)(par ^ 1) * Bsz * KA;
        half_t* actD_R = actD + (size_t)(par) * Bsz * KD;
        half_t* actD_W = actD + (size_t)(par ^ 1) * Bsz * KD;
        float*        mn_cur  = par ? mean1 : mean0;
        const float*  mn_prv  = par ? mean0 : mean1;

        // ========== PHASE 1: aLSTM_t || dLSTM_{t-1} || outproj_{t-2} =======
        if (t < Tsteps) {
            f32x4 accA = {0.f,0.f,0.f,0.f};
            #pragma unroll
            for (int i = 0; i < NMA; ++i) {
                f16x8 av = *(const f16x8*)(lA + i * 32);
                accA = __builtin_amdgcn_mfma_f32_16x16x32_f16(av, bvA[i], accA, 0, 0, 0);
            }
            #pragma unroll
            for (int r = 0; r < 4; ++r)
                gredA[kq][btile][(kh << 2) + r][m15] = accA[r];
        }
        if (t >= 1 && t <= Tsteps) {
            f32x4 accD = {0.f,0.f,0.f,0.f};
            #pragma unroll
            for (int i = 0; i < NMD; ++i) {
                f16x8 av = *(const f16x8*)(lD + i * 32);
                accD = __builtin_amdgcn_mfma_f32_16x16x32_f16(av, bvD[i], accD, 0, 0, 0);
            }
            #pragma unroll
            for (int r = 0; r < 4; ++r)
                gredD[kq][btile][(kh << 2) + r][m15] = accD[r];
        }
        if (t >= 2) {
            // outproj t-2: acts = [dh_{t-2} | ctx_{t-2}] = actD_R[1024+k] / actD_W[1024+k]
            const int b_o = tid & 31;
            const int ks  = tid >> 5;
            const half_t* wrow = Wo + (size_t)blk * (DRNN + ENCD) + ks * 96;
            const half_t* dhb  = actD_R + (size_t)b_o * KD + 1024;
            const half_t* cxb  = actD_W + (size_t)b_o * KD + 1024;
            float outacc = 0.f;
            #pragma unroll
            for (int cc = 0; cc < 12; ++cc) {
                const int k = ks * 96 + cc * 8;
                f16x8 wv = *(const f16x8*)(wrow + cc * 8);   // plain, L2-hot
                f16x8 av = ld_agent_f16x8((k < DRNN ? dhb : cxb) + k);
                #pragma unroll
                for (int e = 0; e < 8; ++e)
                    outacc += (float)wv[e] * (float)av[e];
            }
            lred[ks][b_o] = outacc;
        }
        __syncthreads();
        // concurrent epilogues
        if (tid < 128) {
            if (t < Tsteps) {
                const int ul = tid >> 5;
                const int bq = tid & 31;
                const int bt = bq >> 4;
                const int nn = bq & 15;
                float g[4];
                #pragma unroll
                for (int gi = 0; gi < 4; ++gi) {
                    const int mr = (gi << 2) + ul;
                    g[gi] = gredA[0][bt][mr][nn] + gredA[1][bt][mr][nn]
                          + gredA[2][bt][mr][nn] + gredA[3][bt][mr][nn] + bsA[gi];
                }
                float si = 1.f / (1.f + expf(-g[0]));
                float sf = 1.f / (1.f + expf(-g[1]));
                float so = 1.f / (1.f + expf(-g[3]));
                cA = sf * cA + si * tanh_f(g[2]);
                float hval = so * tanh_f(cA);
                hstA[ul][bq] = (half_t)hval;
                part[ul][bq][0] = hval * wp0;
                part[ul][bq][1] = hval * wp1;
            }
        } else if (tid < 256) {
            if (t >= 1 && t <= Tsteps) {
                const int lt = tid - 128;
                const int ul = lt >> 5;
                const int bq = lt & 31;
                const int bt = bq >> 4;
                const int nn = bq & 15;
                float g[4];
                #pragma unroll
                for (int gi = 0; gi < 4; ++gi) {
                    const int mr = (gi << 2) + ul;
                    g[gi] = gredD[0][bt][mr][nn] + gredD[1][bt][mr][nn]
                          + gredD[2][bt][mr][nn] + gredD[3][bt][mr][nn] + bsD[gi];
                }
                float si = 1.f / (1.f + expf(-g[0]));
                float sf = 1.f / (1.f + expf(-g[1]));
                float so = 1.f / (1.f + expf(-g[3]));
                cD = sf * cD + si * tanh_f(g[2]);
                hstD[ul][bq] = (half_t)(so * tanh_f(cD));
            }
        } else if (tid < 288) {
            if (t >= 2) {
                const int b = tid - 256;
                float s = 0.f;
                #pragma unroll
                for (int q = 0; q < 16; ++q) s += lred[q][b];
                st_agent_f32(&logits[(size_t)b * Tsteps * NSYM + (size_t)(t - 2) * NSYM + blk],
                             s + ob[blk]);
            }
        } else {
            // xpre_{t+1} -> actA_W slot [0,256)  (2048 u64 over 224 threads)
            if (t + 1 < Tsteps) {
                const unsigned long long* src =
                    (const unsigned long long*)(xpre + (size_t)(t + 1) * Bsz * PRE);
                for (int j = tid - 288; j < 2048; j += 224) {
                    const int e = j << 2;
                    const int b = e >> 8;
                    const int c = e & 255;
                    unsigned long long v = src[j];
                    st_agent_u64((unsigned long long*)(actA_W + (size_t)b * KA + c), v);
                }
            }
        }
        __syncthreads();
        // coalesced publishes (8B sc1): ah -> actA_W & actD_W; dh -> actD_W
        if (t < Tsteps && tid < 32) {
            union { unsigned long long u; half_t h[4]; } pk;
            #pragma unroll
            for (int q = 0; q < 4; ++q) pk.h[q] = hstA[q][tid];
            st_agent_u64((unsigned long long*)(actA_W + (size_t)tid * KA + 256 + u0), pk.u);
            st_agent_u64((unsigned long long*)(actD_W + (size_t)tid * KD + u0), pk.u);
            float p0 = part[0][tid][0] + part[1][tid][0] + part[2][tid][0] + part[3][tid][0];
            float p1 = part[0][tid][1] + part[1][tid][1] + part[2][tid][1] + part[3][tid][1];
            union { float2 f; unsigned long long u; } pp;
            pp.f.x = p0; pp.f.y = p1;
            st_agent_u64((unsigned long long*)(partials + ((size_t)tid * 256 + blk) * 2), pp.u);
        }
        if (t >= 1 && t <= Tsteps && tid >= 64 && tid < 96) {
            const int b = tid - 64;
            union { unsigned long long u; half_t h[4]; } pk;
            #pragma unroll
            for (int q = 0; q < 4; ++q) pk.h[q] = hstD[q][b];
            st_agent_u64((unsigned long long*)(actD_W + (size_t)b * KD + 1024 + u0), pk.u);
        }
        if (t <= Tsteps) { ++ph; g_arrive(flags, ph); g_wait(flags, ph, grp, grank); }

        // ================= PHASE 2: att_t ==================================
        if (t < Tsteps) {
            const int abt = blk >> 3;   // batch
            const int dt  = blk & 7;    // d-tile
            float p0 = 0.f, p1 = 0.f;
            if (tid < 256) {
                union { unsigned long long u; float2 f; } pv;
                pv.u = ld_agent_u64((const unsigned long long*)(partials + ((size_t)abt * 256 + tid) * 2));
                p0 = pv.f.x; p1 = pv.f.y;
            }
            #pragma unroll
            for (int off = 32; off > 0; off >>= 1) {
                p0 += __shfl_down(p0, off, 64);
                p1 += __shfl_down(p1, off, 64);
            }
            if (lane == 0) { wred8[wave][0] = p0; wred8[wave][1] = p1; }
            __syncthreads();
            if (tid == 0) {
                float q0 = attbp[0], q1 = attbp[1];
                #pragma unroll
                for (int w = 0; w < 8; ++w) { q0 += wred8[w][0]; q1 += wred8[w][1]; }
                float mn = ld_agent_f32(&mn_prv[abt]) + expf(q0) * 1.0f;  // MEAN_COEFF
                float sc = expf(q1) * 10.0f;                              // SCALE_COEFF
                if (dt == 0) {
                    st_agent_f32(&mn_cur[abt], mn);
                    st_agent_f32(&ps[(size_t)abt * Tsteps * 2 + (size_t)t * 2 + 0], q0);
                    st_agent_f32(&ps[(size_t)abt * Tsteps * 2 + (size_t)t * 2 + 1], q1);
                }
                bc2[0] = mn; bc2[1] = sc;
            }
            __syncthreads();
            const float mn = bc2[0], sc = bc2[1];
            const float inv_s = 1.f / sc;
            const float coef = 0.3989422804014327f * inv_s;
            const int len = mlen[abt];
            {
                float z = ((float)tid - mn) * inv_s;
                wsh[tid] = (tid < len) ? expf(-0.5f * z * z) * coef : 0.f;
            }
            __syncthreads();
            if (tid < 64) {
                const int l = (dt << 6) + tid;
                st_agent_f32(&aligns[(size_t)abt * Tsteps * Lmem + (size_t)t * Lmem + l], wsh[l]);
            }
            int lo = (int)fmaxf(0.f, floorf(mn - 9.f * sc));
            int hi = (int)fminf((float)len, ceilf(mn + 9.f * sc) + 1.f);
            const int d8 = (dt << 6) + (wave << 3);
            const half_t* mb = mem16 + (size_t)abt * Lmem * ENCD + d8;
            float acc[8] = {0.f,0.f,0.f,0.f,0.f,0.f,0.f,0.f};
            for (int l = lo + lane; l < hi; l += 64) {
                f16x8 mv = *(const f16x8*)(mb + (size_t)l * ENCD);   // plain, L2-hot
                float w = wsh[l];
                #pragma unroll
                for (int j = 0; j < 8; ++j) acc[j] += w * (float)mv[j];
            }
            #pragma unroll
            for (int off = 32; off > 0; off >>= 1) {
                #pragma unroll
                for (int j = 0; j < 8; ++j) acc[j] += __shfl_down(acc[j], off, 64);
            }
            if (lane == 0) {
                union { unsigned long long u; half_t h[4]; } pk0, pk1;
                #pragma unroll
                for (int j = 0; j < 4; ++j) { pk0.h[j] = (half_t)acc[j]; pk1.h[j] = (half_t)acc[4 + j]; }
                st_agent_u64((unsigned long long*)(actA_W + (size_t)abt * KA + CTXA0 + d8), pk0.u);
                st_agent_u64((unsigned long long*)(actA_W + (size_t)abt * KA + CTXA0 + d8 + 4), pk1.u);
                st_agent_u64((unsigned long long*)(actD_W + (size_t)abt * KD + CTXD0 + d8), pk0.u);
                st_agent_u64((unsigned long long*)(actD_W + (size_t)abt * KD + CTXD0 + d8 + 4), pk1.u);
            }

            // ---- bar2 + in-window prefetch (uniform; non-ctx fragments) ----
            ++ph; g_arrive(flags, ph);
            const half_t* baseAW = actA_W + (size_t)bb * KA + kq * KAQ + (kh << 3);
            const half_t* baseDW = actD_W + (size_t)bb * KD + kq * KDQ + (kh << 3);
            if (t + 1 < Tsteps) {
                #pragma unroll
                for (int i = 0; i < NMA; ++i)
                    if (i < preA) { bvA[i] = ld_agent_f16x8(baseAW + i * 32); keep16(bvA[i]); }
            }
            #pragma unroll
            for (int i = 0; i < NMD; ++i)
                if (i < preD) { bvD[i] = ld_agent_f16x8(baseDW + i * 32); keep16(bvD[i]); }
            g_wait(flags, ph, grp, grank);
            // post-wait: ctx-tail fragments
            if (t + 1 < Tsteps) {
                #pragma unroll
                for (int i = 0; i < NMA; ++i)
                    if (i >= preA) bvA[i] = ld_agent_f16x8(baseAW + i * 32);
            }
            #pragma unroll
            for (int i = 0; i < NMD; ++i)
                if (i >= preD) bvD[i] = ld_agent_f16x8(baseDW + i * 32);
        }
    }
}

// ---------------------------------------------------------------------------
extern "C" void kernel_launch(void* const* d_in, const int* in_sizes, int n_in,
                              void* d_out, int out_size, void* d_ws, size_t ws_size,
                              hipStream_t stream)
{
    (void)in_sizes; (void)n_in; (void)out_size; (void)ws_size;
    const float* memory = (const float*)d_in[0];
    const float* din    = (const float*)d_in[1];
    const int*   mlen   = (const int*)d_in[2];
    const float* pW1    = (const float*)d_in[3];
    const float* pb1    = (const float*)d_in[4];
    const float* pW2    = (const float*)d_in[5];
    const float* pb2    = (const float*)d_in[6];
    const float* aWih   = (const float*)d_in[7];
    const float* aWhh   = (const float*)d_in[8];
    const float* abih   = (const float*)d_in[9];
    const float* abhh   = (const float*)d_in[10];
    const float* attWp  = (const float*)d_in[11];
    const float* attbp  = (const float*)d_in[12];
    const float* dWih   = (const float*)d_in[13];
    const float* dWhh   = (const float*)d_in[14];
    const float* dbih   = (const float*)d_in[15];
    const float* dbhh   = (const float*)d_in[16];
    const float* oW     = (const float*)d_in[17];
    const float* ob     = (const float*)d_in[18];

    float* logits = (float*)d_out;
    float* aligns = logits + (size_t)Bsz * Tsteps * NSYM;
    float* ps     = aligns + (size_t)Bsz * Tsteps * Lmem;

    char* base = (char*)d_ws;
    auto alloc = [&](size_t bytes) -> char* {
        char* p = base; base += (bytes + 255) & ~(size_t)255; return p;
    };
    half_t* Wcat_a = (half_t*)alloc((size_t)4096 * KA * 2);
    half_t* Wcat_d = (half_t*)alloc((size_t)4096 * KD * 2);
    half_t* Wo     = (half_t*)alloc((size_t)NSYM * (DRNN + ENCD) * 2);
    float*  bsum_a = (float*)alloc(4096 * 4);
    float*  bsum_d = (float*)alloc(4096 * 4);
    half_t* xpre   = (half_t*)alloc((size_t)Tsteps * Bsz * PRE * 2);
    half_t* mem16  = (half_t*)alloc((size_t)Bsz * Lmem * ENCD * 2);
    half_t* actA   = (half_t*)alloc((size_t)2 * Bsz * KA * 2);
    half_t* actD   = (half_t*)alloc((size_t)2 * Bsz * KD * 2);
    float*  mean0  = (float*)alloc(Bsz * 4);
    float*  mean1  = (float*)alloc(Bsz * 4);
    float*  partials = (float*)alloc((size_t)Bsz * 256 * 2 * 4);
    unsigned* flags  = (unsigned*)alloc(272 * 16 * 4);

    (void)hipMemsetAsync(actA, 0, (size_t)2 * Bsz * KA * 2, stream);
    (void)hipMemsetAsync(actD, 0, (size_t)2 * Bsz * KD * 2, stream);
    (void)hipMemsetAsync(mean0, 0, Bsz * 4, stream);
    (void)hipMemsetAsync(mean1, 0, Bsz * 4, stream);
    (void)hipMemsetAsync(flags, 0, 272 * 16 * 4, stream);

    conv_lstm_w<PRE + ENCD, ARNN, PRE><<<4096, 256, 0, stream>>>(
        aWih, aWhh, abih, abhh, Wcat_a, bsum_a);
    conv_lstm_w<ARNN + ENCD, DRNN, ARNN><<<4096, 256, 0, stream>>>(
        dWih, dWhh, dbih, dbhh, Wcat_d, bsum_d);
    conv_mat<<<768, 256, 0, stream>>>(oW, Wo, NSYM * (DRNN + ENCD));
    conv_mat<<<4096, 256, 0, stream>>>(memory, mem16, Bsz * Lmem * ENCD);
    prenet_kernel<<<Tsteps * Bsz / 8, 256, 0, stream>>>(din, pW1, pb1, pW2, pb2, xpre);
    xpre0_copy<<<32, 128, 0, stream>>>(xpre, actA);

    decoder_persistent<<<256, 512, 0, stream>>>(
        Wcat_a, bsum_a, Wcat_d, bsum_d, Wo, ob, xpre,
        attWp, attbp, mlen, mem16,
        actA, actD, mean0, mean1, partials,
        logits, aligns, ps,
        flags);
}